// Round 9
// baseline (307.738 us; speedup 1.0000x reference)
//
#include <hip/hip_runtime.h>

// Problem constants: V=100000, H=128, B=1024, L=512
#define V_TOK 100000
#define GAT_H 128
#define GAT_L 512
#define GAT_B 1024
#define CHUNK 32  // consecutive positions per wave; loads CHUNK+1 rows (amp 1.031x)

typedef float v2f __attribute__((ext_vector_type(2)));

__device__ __forceinline__ float readlane_f(float v, int l) {
    return __int_as_float(__builtin_amdgcn_readlane(__float_as_int(v), l));
}

// ---- kernel 1: per-token a2-dots t2[v] = emb[v].a2 (+ fp8 shadow) ----
// ALGEBRA: softmax([s0,s1]) depends only on s0-s1 = t2[tok_l]-t2[tok_{l+1}]+S2
// -- the a1 half of the weight vector cancels; only the t2 table is needed.
// Two tokens per wave (float4 loads). FP8: also writes an OCP e4m3 shadow of
// emb (128 B/row, 2 lines/gather). Dots from f32 rows -> scores full precision.
// Wave id V/2 computes S2 = sum(a2) (merged sums dispatch).
template<int FP8>
__global__ __launch_bounds__(256) void k_tok(const float* __restrict__ emb,
                                             const float* __restrict__ a,
                                             float* __restrict__ t2,
                                             unsigned char* __restrict__ emb8,
                                             float* __restrict__ sbuf) {
    const int wid  = (blockIdx.x * blockDim.x + threadIdx.x) >> 6;
    const int lane = threadIdx.x & 63;
    if (wid > V_TOK / 2) return;

    if (wid == V_TOK / 2) {
        const float2 a2 = ((const float2*)(a + GAT_H))[lane];
        float s2 = a2.x + a2.y;
        #pragma unroll
        for (int m = 32; m >= 1; m >>= 1) s2 += __shfl_xor(s2, m, 64);
        if (lane == 0) sbuf[0] = s2;
        return;
    }

    const int half = lane >> 5;           // which of the two tokens
    const int sub  = lane & 31;           // position within the row (4 elems)
    const int tok  = 2 * wid + half;
    const float4 e  = ((const float4*)(emb + (size_t)tok * GAT_H))[sub];
    const float4 A2 = ((const float4*)(a + GAT_H))[sub];

    if constexpr (FP8) {
        int p = 0;
        p = __builtin_amdgcn_cvt_pk_fp8_f32(e.x, e.y, p, false);  // low word
        p = __builtin_amdgcn_cvt_pk_fp8_f32(e.z, e.w, p, true);   // high word
        ((int*)(emb8 + (size_t)tok * GAT_H))[sub] = p;            // 4 B/lane
    }

    float d2 = e.x * A2.x + e.y * A2.y + e.z * A2.z + e.w * A2.w;
    #pragma unroll
    for (int m = 16; m >= 1; m >>= 1) d2 += __shfl_xor(d2, m, 64);
    if (sub == 0) t2[tok] = d2;
}

// ---- kernel 2: main. One wave per CHUNK consecutive positions of one b. ----
// Burst structure (round 5) + collapsed softmax (round 7) + this round:
//   - CHUNK=32: halves per-wave head chains and fixed prologue overhead
//   - issue order: t2 gather FIRST, then 33 row gathers, then the att pass
//     (waits only on the t2 gather, which completes under row-issue shadow)
//   - cvt-carry: each fp8 row converted to f32 exactly once (R = Rn carry)
// Corrected cost model (round-7 post-mortem): VALU issue is ~5 us total;
// k_main is dominated by the 268 MB nt-store drain (~43 us at the 6.4 TB/s
// ceiling the harness fills demonstrate) + mixed-stream read latency.
template<int FP8>
__global__ __launch_bounds__(256) void k_main(const float* __restrict__ emb,
                                              const unsigned char* __restrict__ emb8,
                                              const int* __restrict__ seq,
                                              const int* __restrict__ seq_l,
                                              const float* __restrict__ t2,
                                              const float* __restrict__ sbuf,
                                              float* __restrict__ out) {
    const int wid  = (blockIdx.x * blockDim.x + threadIdx.x) >> 6;
    const int lane = threadIdx.x & 63;
    const int n_chunks = GAT_L / CHUNK;               // 16
    const int b  = wid >> 4;
    const int l0 = (wid & (n_chunks - 1)) * CHUNK;
    if (b >= GAT_B) return;

    const int sl = __builtin_amdgcn_readfirstlane(seq_l[b]);
    const float S2 = sbuf[0];

    // Lane i (i<=CHUNK) -> token l0+i; higher lanes duplicate lane CHUNK.
    // Last chunk clamps 512->511; that slot feeds only position 511's "next",
    // consumed only if valid(l=511) -- impossible since sl <= 511.
    int li = l0 + (lane < CHUNK + 1 ? lane : CHUNK);
    if (li > GAT_L - 1) li = GAT_L - 1;
    const int   tokv = seq[b * GAT_L + li];
    const float t2v  = t2[tokv];                      // issued first: 4 B gather

    float2* obase = (float2*)(out + ((size_t)b * GAT_L + l0) * GAT_H);

    if constexpr (FP8) {
        // ---- burst: 33 row gathers issued before any dependent compute ----
        unsigned short rows[CHUNK + 1];               // 2 fp8 elems per lane
        #pragma unroll
        for (int k = 0; k <= CHUNK; ++k) {
            const int tk = __builtin_amdgcn_readlane(tokv, k);   // SGPR base
            rows[k] = *((const unsigned short*)(emb8 + (size_t)tk * GAT_H) + lane);
        }

        // ---- per-position pass (lanes 0..CHUNK-1), waits only on t2v ----
        const float t2nx  = __shfl_down(t2v, 1, 64);  // t2 of token l0+lane+1
        const int   l     = l0 + lane;
        const bool  valid = (l < sl - 1);
        const float ex    = __expf(t2v - t2nx + S2);  // exp(s0 - s1)
        float att1 = 1.0f / (1.0f + ex);
        att1 = valid ? att1 : 0.0f;
        const float att0 = 1.0f - att1;               // invalid -> exactly 1
        const float cc   = valid ? ((float)(sl - l) - att1) : 0.0f;

        // ---- store loop: o = att0*R + att1*Rn + c; each row cvt'd once ----
        v2f R = __builtin_amdgcn_cvt_pk_f32_fp8((int)rows[0], false);
        #pragma unroll
        for (int k = 0; k < CHUNK; ++k) {
            const v2f Rn = __builtin_amdgcn_cvt_pk_f32_fp8((int)rows[k + 1], false);
            const float a0 = readlane_f(att0, k);
            const float a1 = readlane_f(att1, k);
            const float c  = readlane_f(cc, k);
            v2f o2;
            o2.x = fmaf(a0, R.x, fmaf(a1, Rn.x, c));
            o2.y = fmaf(a0, R.y, fmaf(a1, Rn.y, c));
            __builtin_nontemporal_store(o2, (v2f*)(obase + (size_t)k * 64 + lane));
            R = Rn;
        }
    } else {
        // f32 fallback: same structure on the original table
        float2 rows[CHUNK + 1];
        #pragma unroll
        for (int k = 0; k <= CHUNK; ++k) {
            const int tk = __builtin_amdgcn_readlane(tokv, k);
            rows[k] = ((const float2*)(emb + (size_t)tk * GAT_H))[lane];
        }
        const float t2nx  = __shfl_down(t2v, 1, 64);
        const int   l     = l0 + lane;
        const bool  valid = (l < sl - 1);
        const float ex    = __expf(t2v - t2nx + S2);
        float att1 = 1.0f / (1.0f + ex);
        att1 = valid ? att1 : 0.0f;
        const float att0 = 1.0f - att1;
        const float cc   = valid ? ((float)(sl - l) - att1) : 0.0f;
        #pragma unroll
        for (int k = 0; k < CHUNK; ++k) {
            const float a0 = readlane_f(att0, k);
            const float a1 = readlane_f(att1, k);
            const float c  = readlane_f(cc, k);
            const float2 R  = rows[k];
            const float2 Rn = rows[k + 1];
            v2f o2;
            o2.x = fmaf(a0, R.x, fmaf(a1, Rn.x, c));
            o2.y = fmaf(a0, R.y, fmaf(a1, Rn.y, c));
            __builtin_nontemporal_store(o2, (v2f*)(obase + (size_t)k * 64 + lane));
        }
    }
}

extern "C" void kernel_launch(void* const* d_in, const int* in_sizes, int n_in,
                              void* d_out, int out_size, void* d_ws, size_t ws_size,
                              hipStream_t stream) {
    const float* emb   = (const float*)d_in[0];
    const float* a     = (const float*)d_in[1];
    const int*   seq   = (const int*)d_in[2];
    const int*   seq_l = (const int*)d_in[3];
    float* out = (float*)d_out;

    const size_t emb8_bytes = (size_t)V_TOK * GAT_H;                    // 12.8 MB
    const size_t t2_bytes   = (size_t)V_TOK * sizeof(float);            // 400 KB
    const size_t need8      = emb8_bytes + t2_bytes + 16;

    const int tok_waves  = V_TOK / 2 + 1;
    const int tok_blocks = (tok_waves * 64 + 255) / 256;
    const int main_waves  = GAT_B * (GAT_L / CHUNK);                    // 16384
    const int main_blocks = (main_waves * 64 + 255) / 256;

    if (ws_size >= need8) {
        unsigned char* emb8 = (unsigned char*)d_ws;
        float* t2   = (float*)((char*)d_ws + emb8_bytes);
        float* sbuf = (float*)((char*)t2 + t2_bytes);
        k_tok<1><<<tok_blocks, 256, 0, stream>>>(emb, a, t2, emb8, sbuf);
        k_main<1><<<main_blocks, 256, 0, stream>>>(emb, emb8, seq, seq_l, t2, sbuf, out);
    } else {
        // f32 fallback if workspace can't hold the shadow
        float* t2   = (float*)d_ws;
        float* sbuf = (float*)((char*)t2 + t2_bytes);
        k_tok<0><<<tok_blocks, 256, 0, stream>>>(emb, a, t2, nullptr, sbuf);
        k_main<0><<<main_blocks, 256, 0, stream>>>(emb, nullptr, seq, seq_l, t2, sbuf, out);
    }
}

// Round 10
// 303.461 us; speedup vs baseline: 1.0141x; 1.0141x over previous
//
#include <hip/hip_runtime.h>

// Problem constants: V=100000, H=128, B=1024, L=512
#define V_TOK 100000
#define GAT_H 128
#define GAT_L 512
#define GAT_B 1024
#define CHUNK 16  // consecutive positions per wave; loads CHUNK+1 rows
                  // (CHUNK=32 regressed in round 8: halved TLP cost more than
                  //  the saved prologues -- keep 32K waves for latency hiding)

typedef float v2f __attribute__((ext_vector_type(2)));

__device__ __forceinline__ float readlane_f(float v, int l) {
    return __int_as_float(__builtin_amdgcn_readlane(__float_as_int(v), l));
}

// ---- kernel 1: per-token a2-dots t2[v] = emb[v].a2 (+ fp8 shadow) ----
// ALGEBRA: softmax([s0,s1]) depends only on s0-s1 = t2[tok_l]-t2[tok_{l+1}]+S2
// -- the a1 half of the weight vector cancels; only the t2 table is needed.
// Two tokens per wave (float4 loads). FP8: also writes an OCP e4m3 shadow of
// emb (128 B/row, 2 lines/gather). Dots from f32 rows -> scores full precision.
// Wave id V/2 computes S2 = sum(a2) (merged sums dispatch).
template<int FP8>
__global__ __launch_bounds__(256) void k_tok(const float* __restrict__ emb,
                                             const float* __restrict__ a,
                                             float* __restrict__ t2,
                                             unsigned char* __restrict__ emb8,
                                             float* __restrict__ sbuf) {
    const int wid  = (blockIdx.x * blockDim.x + threadIdx.x) >> 6;
    const int lane = threadIdx.x & 63;
    if (wid > V_TOK / 2) return;

    if (wid == V_TOK / 2) {
        const float2 a2 = ((const float2*)(a + GAT_H))[lane];
        float s2 = a2.x + a2.y;
        #pragma unroll
        for (int m = 32; m >= 1; m >>= 1) s2 += __shfl_xor(s2, m, 64);
        if (lane == 0) sbuf[0] = s2;
        return;
    }

    const int half = lane >> 5;           // which of the two tokens
    const int sub  = lane & 31;           // position within the row (4 elems)
    const int tok  = 2 * wid + half;
    const float4 e  = ((const float4*)(emb + (size_t)tok * GAT_H))[sub];
    const float4 A2 = ((const float4*)(a + GAT_H))[sub];

    if constexpr (FP8) {
        int p = 0;
        p = __builtin_amdgcn_cvt_pk_fp8_f32(e.x, e.y, p, false);  // low word
        p = __builtin_amdgcn_cvt_pk_fp8_f32(e.z, e.w, p, true);   // high word
        ((int*)(emb8 + (size_t)tok * GAT_H))[sub] = p;            // 4 B/lane
    }

    float d2 = e.x * A2.x + e.y * A2.y + e.z * A2.z + e.w * A2.w;
    #pragma unroll
    for (int m = 16; m >= 1; m >>= 1) d2 += __shfl_xor(d2, m, 64);
    if (sub == 0) t2[tok] = d2;
}

// ---- kernel 2: main. One wave per CHUNK consecutive positions of one b. ----
// Round-7 structure (best: 304.5 us) + the two harmless round-8 backports:
//   - burst issued BEFORE the exp/att chain (burst depends only on tokv, so
//     the expf latency no longer delays the 17 row-load issues)
//   - cvt-carry: each fp8 row converted to f32 exactly once (R = Rn carry)
// Cost model (confirmed rounds 7-8): k_main ~75 us = 268 MB nt-store drain
// (~43 us at the demonstrated 6.4 TB/s ceiling) + mixed-stream read latency;
// VALU issue ~5 us. Timed window also contains ~209 us of harness poison
// fills (1 GiB ws + 268 MB out) we cannot touch.
template<int FP8>
__global__ __launch_bounds__(256) void k_main(const float* __restrict__ emb,
                                              const unsigned char* __restrict__ emb8,
                                              const int* __restrict__ seq,
                                              const int* __restrict__ seq_l,
                                              const float* __restrict__ t2,
                                              const float* __restrict__ sbuf,
                                              float* __restrict__ out) {
    const int wid  = (blockIdx.x * blockDim.x + threadIdx.x) >> 6;
    const int lane = threadIdx.x & 63;
    const int n_chunks = GAT_L / CHUNK;               // 32
    const int b  = wid / n_chunks;
    const int l0 = (wid - b * n_chunks) * CHUNK;
    if (b >= GAT_B) return;

    const int sl = __builtin_amdgcn_readfirstlane(seq_l[b]);
    const float S2 = sbuf[0];

    // Lane i (i<=CHUNK) -> token l0+i; higher lanes duplicate lane CHUNK.
    // Last chunk clamps 512->511; that slot feeds only position 511's "next",
    // consumed only if valid(l=511) -- impossible since sl <= 511.
    int li = l0 + (lane < CHUNK + 1 ? lane : CHUNK);
    if (li > GAT_L - 1) li = GAT_L - 1;
    const int   tokv = seq[b * GAT_L + li];
    const float t2v  = t2[tokv];                      // issued first: 4 B gather

    float2* obase = (float2*)(out + ((size_t)b * GAT_L + l0) * GAT_H);

    if constexpr (FP8) {
        // ---- burst: 17 row gathers issued before any dependent compute ----
        unsigned short rows[CHUNK + 1];               // 2 fp8 elems per lane
        #pragma unroll
        for (int k = 0; k <= CHUNK; ++k) {
            const int tk = __builtin_amdgcn_readlane(tokv, k);   // SGPR base
            rows[k] = *((const unsigned short*)(emb8 + (size_t)tk * GAT_H) + lane);
        }

        // ---- per-position pass (lanes 0..CHUNK-1), waits only on t2v ----
        const float t2nx  = __shfl_down(t2v, 1, 64);  // t2 of token l0+lane+1
        const int   l     = l0 + lane;
        const bool  valid = (l < sl - 1);
        const float ex    = __expf(t2v - t2nx + S2);  // exp(s0 - s1)
        float att1 = 1.0f / (1.0f + ex);
        att1 = valid ? att1 : 0.0f;
        const float att0 = 1.0f - att1;               // invalid -> exactly 1
        const float cc   = valid ? ((float)(sl - l) - att1) : 0.0f;

        // ---- store loop: o = att0*R + att1*Rn + c; each row cvt'd once ----
        v2f R = __builtin_amdgcn_cvt_pk_f32_fp8((int)rows[0], false);
        #pragma unroll
        for (int k = 0; k < CHUNK; ++k) {
            const v2f Rn = __builtin_amdgcn_cvt_pk_f32_fp8((int)rows[k + 1], false);
            const float a0 = readlane_f(att0, k);
            const float a1 = readlane_f(att1, k);
            const float c  = readlane_f(cc, k);
            v2f o2;
            o2.x = fmaf(a0, R.x, fmaf(a1, Rn.x, c));
            o2.y = fmaf(a0, R.y, fmaf(a1, Rn.y, c));
            __builtin_nontemporal_store(o2, (v2f*)(obase + (size_t)k * 64 + lane));
            R = Rn;
        }
    } else {
        // f32 fallback: same structure on the original table
        float2 rows[CHUNK + 1];
        #pragma unroll
        for (int k = 0; k <= CHUNK; ++k) {
            const int tk = __builtin_amdgcn_readlane(tokv, k);
            rows[k] = ((const float2*)(emb + (size_t)tk * GAT_H))[lane];
        }
        const float t2nx  = __shfl_down(t2v, 1, 64);
        const int   l     = l0 + lane;
        const bool  valid = (l < sl - 1);
        const float ex    = __expf(t2v - t2nx + S2);
        float att1 = 1.0f / (1.0f + ex);
        att1 = valid ? att1 : 0.0f;
        const float att0 = 1.0f - att1;
        const float cc   = valid ? ((float)(sl - l) - att1) : 0.0f;
        #pragma unroll
        for (int k = 0; k < CHUNK; ++k) {
            const float a0 = readlane_f(att0, k);
            const float a1 = readlane_f(att1, k);
            const float c  = readlane_f(cc, k);
            const float2 R  = rows[k];
            const float2 Rn = rows[k + 1];
            v2f o2;
            o2.x = fmaf(a0, R.x, fmaf(a1, Rn.x, c));
            o2.y = fmaf(a0, R.y, fmaf(a1, Rn.y, c));
            __builtin_nontemporal_store(o2, (v2f*)(obase + (size_t)k * 64 + lane));
        }
    }
}

extern "C" void kernel_launch(void* const* d_in, const int* in_sizes, int n_in,
                              void* d_out, int out_size, void* d_ws, size_t ws_size,
                              hipStream_t stream) {
    const float* emb   = (const float*)d_in[0];
    const float* a     = (const float*)d_in[1];
    const int*   seq   = (const int*)d_in[2];
    const int*   seq_l = (const int*)d_in[3];
    float* out = (float*)d_out;

    const size_t emb8_bytes = (size_t)V_TOK * GAT_H;                    // 12.8 MB
    const size_t t2_bytes   = (size_t)V_TOK * sizeof(float);            // 400 KB
    const size_t need8      = emb8_bytes + t2_bytes + 16;

    const int tok_waves  = V_TOK / 2 + 1;
    const int tok_blocks = (tok_waves * 64 + 255) / 256;
    const int main_waves  = GAT_B * (GAT_L / CHUNK);                    // 32768
    const int main_blocks = (main_waves * 64 + 255) / 256;

    if (ws_size >= need8) {
        unsigned char* emb8 = (unsigned char*)d_ws;
        float* t2   = (float*)((char*)d_ws + emb8_bytes);
        float* sbuf = (float*)((char*)t2 + t2_bytes);
        k_tok<1><<<tok_blocks, 256, 0, stream>>>(emb, a, t2, emb8, sbuf);
        k_main<1><<<main_blocks, 256, 0, stream>>>(emb, emb8, seq, seq_l, t2, sbuf, out);
    } else {
        // f32 fallback if workspace can't hold the shadow
        float* t2   = (float*)d_ws;
        float* sbuf = (float*)((char*)t2 + t2_bytes);
        k_tok<0><<<tok_blocks, 256, 0, stream>>>(emb, a, t2, nullptr, sbuf);
        k_main<0><<<main_blocks, 256, 0, stream>>>(emb, nullptr, seq, seq_l, t2, sbuf, out);
    }
}